// Round 3
// baseline (719.007 us; speedup 1.0000x reference)
//
#include <hip/hip_runtime.h>

// Dequant: groups of 32 4-bit values packed as 17 int32 words/group
// (16 data words, low byte = two nibbles; word 16 = biased log2 scale).
//
// v3b: persistent double-buffered pipeline (T3 minimum-2-phase, safe form).
// v2 (LDS-staged, stage->syncthreads->compute per block) was dur-neutral vs
// v1 (scalar gathers): read coalescing was not the lever. Remaining
// non-BW suspect: exposed HBM latency per tile (each block serialized
// stage wait -> compute). v3: grid-stride persistent blocks, 2 LDS buffers;
// per tile: sync; issue stage(next) [fire-and-forget global_load_lds];
// compute(cur); next-tile loads fly UNDER compute and the single
// __syncthreads drain per tile only waits the un-landed remainder.
// Also: nontemporal stores (output never re-read; keep L2 for the input
// stream) via native ext_vector type (HIP float4 class is rejected by the
// builtin - that was v3's compile failure), constant-offset LDS reads
// (base+544k folds into ds immediates).
//
// Mandatory traffic: 285 MB read + 537 MB write = 822 MB -> ~131 us floor
// at the fill-measured 6.28 TB/s.

constexpr int kGroupSize = 32;
constexpr int kPGS = kGroupSize / 2 + 1;              // 17 words per packed group

constexpr int kBlock = 256;
constexpr int kGroupsPerTile = 256;
constexpr int kTileWords = kGroupsPerTile * kPGS;     // 4352 words = 17,408 B
constexpr int kVec4PerTile = kGroupsPerTile * kGroupSize / 4;   // 2048 float4
constexpr int kChunkWords = 256;                      // 64 lanes * 16 B = 1 KiB
constexpr int kChunks = kTileWords / kChunkWords;     // 17 (exact)
constexpr int kGrid = 1024;                           // 4 blocks/CU (LDS-limited) x 256 CU

typedef float vfloat4 __attribute__((ext_vector_type(4)));  // builtin-compatible

__device__ __forceinline__ void stage_tile(const int* __restrict__ gsrc,
                                           int* ldst, int wave, int lane)
{
    // 17 x 1 KiB wave-chunks; LDS dest wave-uniform base + lane*16 (linear
    // both sides, rule #21). Fire-and-forget: completion via vmcnt drain at
    // the NEXT __syncthreads.
#pragma unroll
    for (int k = 0; k < 5; ++k) {
        const int c = k * 4 + wave;                   // wave-uniform chunk id
        if (c < kChunks) {
            const int* g = gsrc + c * kChunkWords + lane * 4;
            __builtin_amdgcn_global_load_lds(
                (const __attribute__((address_space(1))) int*)g,
                (__attribute__((address_space(3))) int*)(ldst + c * kChunkWords),
                16 /*bytes: literal*/, 0, 0);
        }
    }
}

__device__ __forceinline__ void compute_tile(const int* __restrict__ tile,
                                             vfloat4* __restrict__ outv,
                                             int t, float clamp_max, float inv_max)
{
    const int gb = (t >> 3) * kPGS;                   // group word-base, k=0
    const int b0 = (t & 7) * 2;                       // k-invariant
#pragma unroll
    for (int k = 0; k < kVec4PerTile / kBlock; ++k) { // 8 float4/thread
        const int base = gb + k * 32 * kPGS;          // +544 words/k -> ds imm offsets
        const int w0 = tile[base + b0];
        const int w1 = tile[base + b0 + 1];           // pairs -> ds_read2_b32
        const int s  = tile[base + kGroupSize / 2];   // scale word (8-lane bcast)

        int e = s - 127;
        e = min(max(e, -126), 127);
        const float coef = ldexpf(1.0f, e) * inv_max; // v_ldexp_f32; 2^e / max_val

        vfloat4 r;                                    // same math as v1/v2 (verified)
        r.x = ((float)(w0 & 15)        - clamp_max) * coef;
        r.y = ((float)((w0 >> 4) & 15) - clamp_max) * coef;
        r.z = ((float)(w1 & 15)        - clamp_max) * coef;
        r.w = ((float)((w1 >> 4) & 15) - clamp_max) * coef;

        // Output is never re-read: bypass L2 allocate, keep it for the input stream.
        __builtin_nontemporal_store(r, &outv[t + kBlock * k]);
    }
}

__global__ __launch_bounds__(kBlock) void dequant_mxfp4_v3_kernel(
    const int* __restrict__ packed,
    const int* __restrict__ ebits_p,
    const int* __restrict__ mbits_p,
    float* __restrict__ out,
    int n_tiles)
{
    __shared__ int tile[2][kTileWords];               // 34,816 B -> 4 blocks/CU

    const int t    = threadIdx.x;
    const int wave = t >> 6;
    const int lane = t & 63;

    int ti = blockIdx.x;
    if (ti >= n_tiles) return;

    // Uniform scalar params (s_load; overlaps prologue staging latency).
    const int ebits = ebits_p[0];
    const int mbits = mbits_p[0];
    const float clamp_max = (float)(1 << ((1 << ebits) - 1));           // 8
    const float inv_max   = 1.0f / (clamp_max * (2.0f - exp2f((float)(-mbits))));  // 1/12

    // Prologue: stage first tile into buffer 0.
    stage_tile(packed + (size_t)ti * kTileWords, tile[0], wave, lane);

    int buf = 0;
    for (; ti < n_tiles; ti += kGrid) {
        // Drain: this wave's outstanding stage loads for tile[buf] have
        // landed; all waves' reads of tile[buf^1] (previous iter) are done,
        // so it is safe to overwrite below.
        __syncthreads();

        const int tn = ti + kGrid;
        if (tn < n_tiles)
            stage_tile(packed + (size_t)tn * kTileWords, tile[buf ^ 1], wave, lane);

        compute_tile(tile[buf],
                     reinterpret_cast<vfloat4*>(out) + (size_t)ti * kVec4PerTile,
                     t, clamp_max, inv_max);
        buf ^= 1;
    }
}

// Scalar tail fallback (v1 body). Not dispatched at the bench shape
// (33,554,432 float4 = 16,384 full tiles exactly); kept for robustness.
__global__ __launch_bounds__(256) void dequant_mxfp4_tail_kernel(
    const int* __restrict__ packed,
    const int* __restrict__ ebits_p,
    const int* __restrict__ mbits_p,
    float* __restrict__ out,
    int v_begin, int n_vec4)
{
    int v = v_begin + blockIdx.x * 256 + threadIdx.x;
    if (v >= n_vec4) return;

    const int ebits = ebits_p[0];
    const int mbits = mbits_p[0];
    const float clamp_max = (float)(1 << ((1 << ebits) - 1));
    const float inv_max   = 1.0f / (clamp_max * (2.0f - exp2f((float)(-mbits))));

    int g  = v >> 3;
    int b0 = (v & 7) * 2;
    int base = g * kPGS;

    int w0 = packed[base + b0];
    int w1 = packed[base + b0 + 1];
    int s  = packed[base + kGroupSize / 2];

    int e = s - 127;
    e = min(max(e, -126), 127);
    float coef = ldexpf(1.0f, e) * inv_max;

    float4 r;
    r.x = ((float)(w0 & 15)        - clamp_max) * coef;
    r.y = ((float)((w0 >> 4) & 15) - clamp_max) * coef;
    r.z = ((float)(w1 & 15)        - clamp_max) * coef;
    r.w = ((float)((w1 >> 4) & 15) - clamp_max) * coef;

    reinterpret_cast<float4*>(out)[v] = r;
}

extern "C" void kernel_launch(void* const* d_in, const int* in_sizes, int n_in,
                              void* d_out, int out_size, void* d_ws, size_t ws_size,
                              hipStream_t stream) {
    const int* packed  = (const int*)d_in[0];
    // d_in[1] = group_size (structural, =32; packing geometry hardcoded)
    const int* ebits_p = (const int*)d_in[2];
    const int* mbits_p = (const int*)d_in[3];
    float* out = (float*)d_out;

    const int n_vec4  = out_size / 4;                 // 33,554,432 float4s
    const int n_tiles = n_vec4 / kVec4PerTile;        // 16,384 tiles
    const int tail    = n_vec4 - n_tiles * kVec4PerTile;

    if (n_tiles > 0) {
        const int grid = n_tiles < kGrid ? n_tiles : kGrid;
        dequant_mxfp4_v3_kernel<<<grid, kBlock, 0, stream>>>(
            packed, ebits_p, mbits_p, out, n_tiles);
    }
    if (tail > 0) {
        const int tgrid = (tail + 255) / 256;
        dequant_mxfp4_tail_kernel<<<tgrid, 256, 0, stream>>>(
            packed, ebits_p, mbits_p, out, n_tiles * kVec4PerTile, n_vec4);
    }
}

// Round 4
// 691.217 us; speedup vs baseline: 1.0402x; 1.0402x over previous
//
#include <hip/hip_runtime.h>

// Dequant: groups of 32 4-bit values packed as 17 int32 words/group
// (16 data words, low byte = two nibbles; word 16 = biased log2 scale).
// out[g*32 + 2b]   = (low_nibble(word b)  - clamp_max) / max_val * 2^(s-127)
// out[g*32 + 2b+1] = (high_nibble(word b) - clamp_max) / max_val * 2^(s-127)
//
// v4 = revert to v1 (best measured: 690.6/690.9 us).
// Session evidence that v1 is at the kernel's roofline:
//  - v2 (fully-coalesced global_load_lds staging, eliminates the 3x read
//    request amplification of the 17-word stride): dur 699.3 (neutral).
//  - v3b (persistent double-buffered pipeline, nontemporal stores):
//    dur 719.0 (worse: 4 blocks/CU vs 8, lock-step loop overhead).
//  - Kernel absent from rocprof top-5 in every round -> K < 337 us;
//    mandatory traffic 285 MB read + 537 MB write = 822 MB -> ~132 us
//    floor at the fill-measured 6.28 TB/s. All structural variants move
//    identical bytes and land within 4% total dur -> K is byte-bound at
//    ~135 us; the remaining ~556 us of dur is harness poison-fill (2 GiB
//    at 78% peak, its own write roofline) + reset chain.
//
// One thread per float4 of output: tid -> g = tid>>3, j0 = (tid&7)*4.
// Output float offset = g*32 + j0 = tid*4  -> perfectly coalesced dwordx4 stores.

constexpr int kGroupSize = 32;
constexpr int kPGS = kGroupSize / 2 + 1;  // 17 words per packed group

__global__ __launch_bounds__(256) void dequant_mxfp4_kernel(
    const int* __restrict__ packed,
    const int* __restrict__ ebits_p,
    const int* __restrict__ mbits_p,
    float* __restrict__ out,
    int n_vec4)
{
    int tid = blockIdx.x * 256 + threadIdx.x;
    if (tid >= n_vec4) return;

    // Uniform scalar params (s_load; effectively free, memory-bound kernel).
    int ebits = ebits_p[0];
    int mbits = mbits_p[0];
    float clamp_max = (float)(1 << ((1 << ebits) - 1));          // 8 for ebits=2
    float inv_max   = 1.0f / (clamp_max * (2.0f - exp2f((float)(-mbits))));  // 1/12

    int g  = tid >> 3;          // group index (8 threads per group)
    int b0 = (tid & 7) * 2;     // first data word this thread handles
    int base = g * kPGS;

    int w0 = packed[base + b0];
    int w1 = packed[base + b0 + 1];
    int s  = packed[base + kGroupSize / 2];  // scale word (8-lane broadcast)

    int e = s - 127;
    e = min(max(e, -126), 127);
    float coef = ldexpf(1.0f, e) * inv_max;  // 2^e / max_val

    float4 r;
    r.x = ((float)(w0 & 15)        - clamp_max) * coef;
    r.y = ((float)((w0 >> 4) & 15) - clamp_max) * coef;
    r.z = ((float)(w1 & 15)        - clamp_max) * coef;
    r.w = ((float)((w1 >> 4) & 15) - clamp_max) * coef;

    reinterpret_cast<float4*>(out)[tid] = r;
}

extern "C" void kernel_launch(void* const* d_in, const int* in_sizes, int n_in,
                              void* d_out, int out_size, void* d_ws, size_t ws_size,
                              hipStream_t stream) {
    const int* packed  = (const int*)d_in[0];
    // d_in[1] = group_size (structural, =32; packing geometry hardcoded)
    const int* ebits_p = (const int*)d_in[2];
    const int* mbits_p = (const int*)d_in[3];
    float* out = (float*)d_out;

    int n_vec4 = out_size / 4;                 // 33,554,432 float4s
    int grid = (n_vec4 + 255) / 256;           // 131,072 blocks
    dequant_mxfp4_kernel<<<grid, 256, 0, stream>>>(packed, ebits_p, mbits_p, out, n_vec4);
}